// Round 1
// baseline (790.617 us; speedup 1.0000x reference)
//
#include <hip/hip_runtime.h>

#define HIDDEN 128
#define NEG_SLOPE 0.2f

static inline size_t align_up(size_t x, size_t a){ return (x + a - 1) & ~(a - 1); }

__device__ __forceinline__ float f4c(const float4 v, int i){
  switch(i){ case 0: return v.x; case 1: return v.y; case 2: return v.z; default: return v.w; }
}

// ---------------- CSR build ----------------

// histogram of dst + weighted in-degree (GCN deg, excluding self-loop)
__global__ void k_hist(const int* __restrict__ dst, const float* __restrict__ w,
                       int* __restrict__ cnt, float* __restrict__ degw, int E){
  int e = blockIdx.x*blockDim.x + threadIdx.x;
  if (e >= E) return;
  int d = dst[e];
  atomicAdd(&cnt[d], 1);
  atomicAdd(&degw[d], w[e]);
}

// per-block inclusive scan of cnt -> incl (stored in rowp), block totals
__global__ void k_scan1(const int* __restrict__ cnt, int* __restrict__ incl,
                        int* __restrict__ blockSums, int N){
  __shared__ int sd[256];
  int t = threadIdx.x;
  int i = blockIdx.x*256 + t;
  int v = (i < N) ? cnt[i] : 0;
  sd[t] = v; __syncthreads();
  for (int off = 1; off < 256; off <<= 1){
    int add = (t >= off) ? sd[t-off] : 0;
    __syncthreads();
    sd[t] += add;
    __syncthreads();
  }
  if (i < N) incl[i] = sd[t];
  if (t == 255) blockSums[blockIdx.x] = sd[255];
}

// single-block scan of block sums -> exclusive offsets (robust to nb>256 via carry loop)
__global__ void k_scan2(const int* __restrict__ blockSums, int* __restrict__ blockOffs, int nb){
  __shared__ int sd[256];
  __shared__ int carry;
  int t = threadIdx.x;
  if (t == 0) carry = 0;
  __syncthreads();
  for (int base = 0; base < nb; base += 256){
    int i = base + t;
    int v = (i < nb) ? blockSums[i] : 0;
    sd[t] = v; __syncthreads();
    for (int off = 1; off < 256; off <<= 1){
      int add = (t >= off) ? sd[t-off] : 0;
      __syncthreads();
      sd[t] += add;
      __syncthreads();
    }
    if (i < nb) blockOffs[i] = carry + sd[t] - v;   // exclusive
    __syncthreads();
    if (t == 0) carry += sd[255];
    __syncthreads();
  }
}

// incl -> exclusive row_ptr (+ cursor copy, + row_ptr[N]=E)
__global__ void k_scan3(int* __restrict__ rowp, const int* __restrict__ cnt,
                        const int* __restrict__ blockOffs, int* __restrict__ cursor,
                        int N, int E){
  int i = blockIdx.x*256 + threadIdx.x;
  if (i < N){
    int excl = rowp[i] - cnt[i] + blockOffs[blockIdx.x];
    rowp[i] = excl;
    cursor[i] = excl;
  }
  if (i == 0) rowp[N] = E;
}

__global__ void k_dinv(float* __restrict__ dinv, int N){
  int i = blockIdx.x*blockDim.x + threadIdx.x;
  if (i < N) dinv[i] = rsqrtf(dinv[i] + 1.0f);   // +1 = self-loop weight; deg>=1 always
}

// scatter edges into CSR buckets; precompute per-edge GCN norm and GAT logit
__global__ void k_scatter(const int* __restrict__ src, const int* __restrict__ dst,
                          const float* __restrict__ w, const float* __restrict__ ssrc,
                          const float* __restrict__ sdst, const float* __restrict__ dinv,
                          int* __restrict__ cursor, int* __restrict__ col_src,
                          float* __restrict__ col_norm, float* __restrict__ col_e, int E){
  int e = blockIdx.x*blockDim.x + threadIdx.x;
  if (e >= E) return;
  int s = src[e], d = dst[e];
  float ww = w[e];
  int pos = atomicAdd(&cursor[d], 1);
  col_src[pos] = s;
  col_norm[pos] = dinv[s]*ww*dinv[d];
  float ee = ssrc[s] + sdst[d];
  col_e[pos] = (ee >= 0.f) ? ee : NEG_SLOPE*ee;
}

// ---------------- dense GEMM: C[M,128] = A[M,128] @ W[128,128], fp32 ----------------
// W fully staged in LDS (64 KB). Thread = 4 rows x 32 cols (acc in 32 float4).
__global__ __launch_bounds__(256) void k_gemm(const float* __restrict__ A,
                                              const float* __restrict__ W,
                                              float* __restrict__ C, int M){
  __shared__ float Wl[HIDDEN*HIDDEN];
  int t = threadIdx.x;
  {
    const float4* Wg4 = (const float4*)W;
    float4* Wl4 = (float4*)Wl;
    #pragma unroll
    for (int i = 0; i < 16; i++) Wl4[i*256 + t] = Wg4[i*256 + t];
  }
  __syncthreads();
  int cg = t & 3;          // col group: cg*32 .. cg*32+31
  int rt = t >> 2;         // 0..63
  long r0 = (long)blockIdx.x*256 + (long)rt*4;
  const float4* A4 = (const float4*)A;
  float4* C4 = (float4*)C;
  const float4* Wl4 = (const float4*)Wl;
  float4 acc[4][8];
  #pragma unroll
  for (int i = 0; i < 4; i++)
    #pragma unroll
    for (int c = 0; c < 8; c++) acc[i][c] = make_float4(0.f,0.f,0.f,0.f);

  for (int k4 = 0; k4 < 32; k4++){
    float4 a[4];
    #pragma unroll
    for (int i = 0; i < 4; i++){
      long r = r0 + i;
      a[i] = (r < M) ? A4[r*32 + k4] : make_float4(0.f,0.f,0.f,0.f);
    }
    #pragma unroll
    for (int kk = 0; kk < 4; kk++){
      int k = k4*4 + kk;
      const float4* wrow = Wl4 + k*32 + cg*8;
      #pragma unroll
      for (int c = 0; c < 8; c++){
        float4 w = wrow[c];
        #pragma unroll
        for (int i = 0; i < 4; i++){
          float av = f4c(a[i], kk);
          acc[i][c].x += av*w.x; acc[i][c].y += av*w.y;
          acc[i][c].z += av*w.z; acc[i][c].w += av*w.w;
        }
      }
    }
  }
  #pragma unroll
  for (int i = 0; i < 4; i++){
    long r = r0 + i;
    if (r < M){
      #pragma unroll
      for (int c = 0; c < 8; c++) C4[r*32 + cg*8 + c] = acc[i][c];
    }
  }
}

// per-node dots: s_src[n] = xp[n].a_src, s_dst[n] = xp[n].a_dst  (one wave per node)
__global__ void k_sdots(const float* __restrict__ xp, const float* __restrict__ a_src,
                        const float* __restrict__ a_dst, float* __restrict__ ssrc,
                        float* __restrict__ sdst, int N){
  int n = blockIdx.x*4 + (threadIdx.x >> 6);
  int lane = threadIdx.x & 63;
  if (n >= N) return;
  const float2* xp2 = (const float2*)xp;
  float2 v  = xp2[(size_t)n*64 + lane];
  float2 as = ((const float2*)a_src)[lane];
  float2 ad = ((const float2*)a_dst)[lane];
  float ps = v.x*as.x + v.y*as.y;
  float pd = v.x*ad.x + v.y*ad.y;
  #pragma unroll
  for (int off = 32; off >= 1; off >>= 1){
    ps += __shfl_xor(ps, off, 64);
    pd += __shfl_xor(pd, off, 64);
  }
  if (lane == 0){ ssrc[n] = ps; sdst[n] = pd; }
}

// ---------------- GAT aggregation (wave per dst node, float2 per lane) ----------------
__global__ void k_gat(const float* __restrict__ xp, const int* __restrict__ rowp,
                      const int* __restrict__ col_src, const float* __restrict__ col_e,
                      const float* __restrict__ ssrc, const float* __restrict__ sdst,
                      const float* __restrict__ b_gat, float* __restrict__ h,
                      float* __restrict__ y, int N){
  int n = blockIdx.x*4 + (threadIdx.x >> 6);
  int lane = threadIdx.x & 63;
  if (n >= N) return;
  int rs = rowp[n], re = rowp[n+1];
  float es = ssrc[n] + sdst[n];
  es = (es >= 0.f) ? es : NEG_SLOPE*es;          // self-loop logit
  // softmax max
  float m = es;
  for (int j = rs + lane; j < re; j += 64) m = fmaxf(m, col_e[j]);
  #pragma unroll
  for (int off = 32; off >= 1; off >>= 1) m = fmaxf(m, __shfl_xor(m, off, 64));
  // softmax denom
  float ssum = 0.f;
  for (int j = rs + lane; j < re; j += 64) ssum += __expf(col_e[j] - m);
  #pragma unroll
  for (int off = 32; off >= 1; off >>= 1) ssum += __shfl_xor(ssum, off, 64);
  ssum += __expf(es - m);
  float inv = 1.f / ssum;
  // weighted sum of xp rows
  const float2* xp2 = (const float2*)xp;
  float a0 = __expf(es - m) * inv;
  float2 v0 = xp2[(size_t)n*64 + lane];
  float2 acc; acc.x = a0*v0.x; acc.y = a0*v0.y;
  for (int j = rs; j < re; j++){
    int s = col_src[j];
    float al = __expf(col_e[j] - m) * inv;
    float2 v = xp2[(size_t)s*64 + lane];
    acc.x += al*v.x; acc.y += al*v.y;
  }
  float2 bb = ((const float2*)b_gat)[lane];
  acc.x += bb.x; acc.y += bb.y;
  ((float2*)h)[(size_t)n*64 + lane] = acc;   // layer-0 feature
  ((float2*)y)[(size_t)n*64 + lane] = acc;   // JK running max init
}

// ---------------- GCN aggregation + ReLU + JK max (wave per dst node) ----------------
__global__ void k_gcn(const float* __restrict__ z, const int* __restrict__ rowp,
                      const int* __restrict__ col_src, const float* __restrict__ col_norm,
                      const float* __restrict__ dinv, const float* __restrict__ bias,
                      float* __restrict__ h, float* __restrict__ y, int N){
  int n = blockIdx.x*4 + (threadIdx.x >> 6);
  int lane = threadIdx.x & 63;
  if (n >= N) return;
  int rs = rowp[n], re = rowp[n+1];
  float di = dinv[n];
  const float2* z2 = (const float2*)z;
  float2 v = z2[(size_t)n*64 + lane];
  float sn = di*di;                              // self-loop norm (w=1)
  float2 acc; acc.x = sn*v.x; acc.y = sn*v.y;
  for (int j = rs; j < re; j++){
    int s = col_src[j];
    float nm = col_norm[j];
    float2 vv = z2[(size_t)s*64 + lane];
    acc.x += nm*vv.x; acc.y += nm*vv.y;
  }
  float2 bb = ((const float2*)bias)[lane];
  acc.x = fmaxf(acc.x + bb.x, 0.f);
  acc.y = fmaxf(acc.y + bb.y, 0.f);
  ((float2*)h)[(size_t)n*64 + lane] = acc;
  float2* y2 = (float2*)y;
  float2 yo = y2[(size_t)n*64 + lane];
  yo.x = fmaxf(yo.x, acc.x); yo.y = fmaxf(yo.y, acc.y);
  y2[(size_t)n*64 + lane] = yo;
}

extern "C" void kernel_launch(void* const* d_in, const int* in_sizes, int n_in,
                              void* d_out, int out_size, void* d_ws, size_t ws_size,
                              hipStream_t stream){
  const float* x      = (const float*)d_in[0];
  const int*   eidx   = (const int*)d_in[1];
  const float* emask  = (const float*)d_in[2];
  const float* W_gat  = (const float*)d_in[3];
  const float* a_src  = (const float*)d_in[4];
  const float* a_dst  = (const float*)d_in[5];
  const float* b_gat  = (const float*)d_in[6];
  const float* W_gcn  = (const float*)d_in[7];
  const float* b_gcn  = (const float*)d_in[8];
  int N = in_sizes[0] / HIDDEN;
  int E = in_sizes[1] / 2;
  const int* src = eidx;
  const int* dst = eidx + E;

  // workspace carve (~62 MB total)
  char* p = (char*)d_ws;
  auto carve = [&](size_t bytes)->char*{ char* q = p; p += align_up(bytes, 512); return q; };
  float* bufA     = (float*)carve((size_t)N*HIDDEN*4);   // xp / z
  float* bufB     = (float*)carve((size_t)N*HIDDEN*4);   // h
  float* ssrc     = (float*)carve((size_t)N*4);
  float* sdst     = (float*)carve((size_t)N*4);
  float* dinv     = (float*)carve((size_t)N*4);          // degw accumulator then rsqrt
  int*   rowp     = (int*)  carve((size_t)(N+1)*4);
  int*   cursor   = (int*)  carve((size_t)N*4);
  int*   cnt      = (int*)  carve((size_t)N*4);
  int*   col_src  = (int*)  carve((size_t)E*4);
  float* col_norm = (float*)carve((size_t)E*4);
  float* col_e    = (float*)carve((size_t)E*4);
  int nb = (N + 255) / 256;
  int*   blockSums = (int*)carve((size_t)nb*4);
  int*   blockOffs = (int*)carve((size_t)nb*4);
  (void)ws_size; (void)n_in; (void)out_size;

  hipMemsetAsync(cnt,  0, (size_t)N*4, stream);
  hipMemsetAsync(dinv, 0, (size_t)N*4, stream);

  int eb  = (E + 255) / 256;
  int gb  = (N + 255) / 256;   // 256 rows per gemm block
  int nwb = (N + 3) / 4;       // 4 waves (nodes) per 256-thread block

  k_hist  <<<eb, 256, 0, stream>>>(dst, emask, cnt, dinv, E);
  k_scan1 <<<nb, 256, 0, stream>>>(cnt, rowp, blockSums, N);
  k_scan2 <<<1,  256, 0, stream>>>(blockSums, blockOffs, nb);
  k_scan3 <<<nb, 256, 0, stream>>>(rowp, cnt, blockOffs, cursor, N, E);
  k_dinv  <<<nb, 256, 0, stream>>>(dinv, N);

  k_gemm  <<<gb, 256, 0, stream>>>(x, W_gat, bufA, N);            // xp = x @ W_gat
  k_sdots <<<nwb,256, 0, stream>>>(bufA, a_src, a_dst, ssrc, sdst, N);
  k_scatter<<<eb,256, 0, stream>>>(src, dst, emask, ssrc, sdst, dinv,
                                   cursor, col_src, col_norm, col_e, E);
  k_gat   <<<nwb,256, 0, stream>>>(bufA, rowp, col_src, col_e, ssrc, sdst,
                                   b_gat, bufB, (float*)d_out, N);

  for (int l = 0; l < 3; l++){
    k_gemm<<<gb, 256, 0, stream>>>(bufB, W_gcn + (size_t)l*HIDDEN*HIDDEN, bufA, N);
    k_gcn <<<nwb,256, 0, stream>>>(bufA, rowp, col_src, col_norm, dinv,
                                   b_gcn + (size_t)l*HIDDEN, bufB, (float*)d_out, N);
  }
}

// Round 2
// 477.842 us; speedup vs baseline: 1.6546x; 1.6546x over previous
//
#include <hip/hip_runtime.h>

#define HIDDEN 128
#define NEG_SLOPE 0.2f

typedef unsigned short ushort_t;
typedef __attribute__((ext_vector_type(8))) short short8;
typedef __attribute__((ext_vector_type(4))) float floatx4;

static inline size_t align_up(size_t x, size_t a){ return (x + a - 1) & ~(a - 1); }

__device__ __forceinline__ ushort_t f2b(float f){
  unsigned u = __float_as_uint(f);
  unsigned r = (u + 0x7FFFu + ((u >> 16) & 1u)) >> 16;
  return (ushort_t)r;
}

__device__ __forceinline__ void fma8(float* acc, uint4 v, float a){
  acc[0] += a * __uint_as_float(v.x << 16);
  acc[1] += a * __uint_as_float(v.x & 0xFFFF0000u);
  acc[2] += a * __uint_as_float(v.y << 16);
  acc[3] += a * __uint_as_float(v.y & 0xFFFF0000u);
  acc[4] += a * __uint_as_float(v.z << 16);
  acc[5] += a * __uint_as_float(v.z & 0xFFFF0000u);
  acc[6] += a * __uint_as_float(v.w << 16);
  acc[7] += a * __uint_as_float(v.w & 0xFFFF0000u);
}

__device__ __forceinline__ uint4 pack8(const float* f){
  uint4 u;
  u.x = (unsigned)f2b(f[0]) | ((unsigned)f2b(f[1]) << 16);
  u.y = (unsigned)f2b(f[2]) | ((unsigned)f2b(f[3]) << 16);
  u.z = (unsigned)f2b(f[4]) | ((unsigned)f2b(f[5]) << 16);
  u.w = (unsigned)f2b(f[6]) | ((unsigned)f2b(f[7]) << 16);
  return u;
}

// ---------------- CSR build (unchanged; verified round 1) ----------------

__global__ void k_hist(const int* __restrict__ dst, const float* __restrict__ w,
                       int* __restrict__ cnt, float* __restrict__ degw, int E){
  int e = blockIdx.x*blockDim.x + threadIdx.x;
  if (e >= E) return;
  int d = dst[e];
  atomicAdd(&cnt[d], 1);
  atomicAdd(&degw[d], w[e]);
}

__global__ void k_scan1(const int* __restrict__ cnt, int* __restrict__ incl,
                        int* __restrict__ blockSums, int N){
  __shared__ int sd[256];
  int t = threadIdx.x;
  int i = blockIdx.x*256 + t;
  int v = (i < N) ? cnt[i] : 0;
  sd[t] = v; __syncthreads();
  for (int off = 1; off < 256; off <<= 1){
    int add = (t >= off) ? sd[t-off] : 0;
    __syncthreads();
    sd[t] += add;
    __syncthreads();
  }
  if (i < N) incl[i] = sd[t];
  if (t == 255) blockSums[blockIdx.x] = sd[255];
}

__global__ void k_scan2(const int* __restrict__ blockSums, int* __restrict__ blockOffs, int nb){
  __shared__ int sd[256];
  __shared__ int carry;
  int t = threadIdx.x;
  if (t == 0) carry = 0;
  __syncthreads();
  for (int base = 0; base < nb; base += 256){
    int i = base + t;
    int v = (i < nb) ? blockSums[i] : 0;
    sd[t] = v; __syncthreads();
    for (int off = 1; off < 256; off <<= 1){
      int add = (t >= off) ? sd[t-off] : 0;
      __syncthreads();
      sd[t] += add;
      __syncthreads();
    }
    if (i < nb) blockOffs[i] = carry + sd[t] - v;
    __syncthreads();
    if (t == 0) carry += sd[255];
    __syncthreads();
  }
}

__global__ void k_scan3(int* __restrict__ rowp, const int* __restrict__ cnt,
                        const int* __restrict__ blockOffs, int* __restrict__ cursor,
                        int N, int E){
  int i = blockIdx.x*256 + threadIdx.x;
  if (i < N){
    int excl = rowp[i] - cnt[i] + blockOffs[blockIdx.x];
    rowp[i] = excl;
    cursor[i] = excl;
  }
  if (i == 0) rowp[N] = E;
}

__global__ void k_dinv(float* __restrict__ dinv, int N){
  int i = blockIdx.x*blockDim.x + threadIdx.x;
  if (i < N) dinv[i] = rsqrtf(dinv[i] + 1.0f);
}

__global__ void k_scatter(const int* __restrict__ src, const int* __restrict__ dst,
                          const float* __restrict__ w, const float* __restrict__ ssrc,
                          const float* __restrict__ sdst, const float* __restrict__ dinv,
                          int* __restrict__ cursor, int* __restrict__ col_src,
                          float* __restrict__ col_norm, float* __restrict__ col_e, int E){
  int e = blockIdx.x*blockDim.x + threadIdx.x;
  if (e >= E) return;
  int s = src[e], d = dst[e];
  float ww = w[e];
  int pos = atomicAdd(&cursor[d], 1);
  col_src[pos] = s;
  col_norm[pos] = dinv[s]*ww*dinv[d];
  float ee = ssrc[s] + sdst[d];
  col_e[pos] = (ee >= 0.f) ? ee : NEG_SLOPE*ee;
}

// ---------------- casts ----------------

// x fp32 -> bf16 (2 elems/thread)
__global__ void k_cast_x(const float* __restrict__ x, unsigned* __restrict__ xb, long n2){
  long i = (long)blockIdx.x*256 + threadIdx.x;
  if (i >= n2) return;
  float2 v = ((const float2*)x)[i];
  xb[i] = (unsigned)f2b(v.x) | ((unsigned)f2b(v.y) << 16);
}

// W_gat + W_gcn[3] -> transposed bf16 Wt[mat][n][k]
__global__ void k_cast_w(const float* __restrict__ Wg, const float* __restrict__ Wc,
                         ushort_t* __restrict__ Wt){
  int i = blockIdx.x*256 + threadIdx.x;       // 4*16384
  int mat = i >> 14, idx = i & 16383;
  int k = idx >> 7, n = idx & 127;
  float v = (mat == 0) ? Wg[idx] : Wc[(mat-1)*16384 + idx];
  Wt[mat*16384 + n*128 + k] = f2b(v);
}

// ---------------- MFMA GEMM: C[M,128](bf16) = A[M,128](bf16) @ W, Wt n-major ----------------
// 4 waves/block, wave = 32 rows x 128 cols; frags loaded straight from global (Wt is L1-hot).
__global__ __launch_bounds__(256) void k_gemm(const ushort_t* __restrict__ A,
                                              const ushort_t* __restrict__ Wt,
                                              ushort_t* __restrict__ C, int M){
  int wave = threadIdx.x >> 6, l = threadIdx.x & 63;
  int q = l >> 4, lm = l & 15;
  int rowBase = blockIdx.x*128 + wave*32;
  floatx4 acc[2][8];
  #pragma unroll
  for (int mt = 0; mt < 2; mt++)
    #pragma unroll
    for (int nt = 0; nt < 8; nt++) acc[mt][nt] = (floatx4){0.f,0.f,0.f,0.f};

  #pragma unroll
  for (int kc = 0; kc < 4; kc++){
    int k0 = kc*32 + q*8;
    short8 a[2];
    #pragma unroll
    for (int mt = 0; mt < 2; mt++){
      long r = rowBase + mt*16 + lm;
      if (r < M) a[mt] = *(const short8*)(A + r*128 + k0);
      else       a[mt] = (short8){0,0,0,0,0,0,0,0};
    }
    #pragma unroll
    for (int nt = 0; nt < 8; nt++){
      short8 b = *(const short8*)(Wt + (nt*16 + lm)*128 + k0);
      acc[0][nt] = __builtin_amdgcn_mfma_f32_16x16x32_bf16(a[0], b, acc[0][nt], 0, 0, 0);
      acc[1][nt] = __builtin_amdgcn_mfma_f32_16x16x32_bf16(a[1], b, acc[1][nt], 0, 0, 0);
    }
  }
  #pragma unroll
  for (int mt = 0; mt < 2; mt++){
    #pragma unroll
    for (int r = 0; r < 4; r++){
      long row = rowBase + mt*16 + q*4 + r;
      if (row < M){
        #pragma unroll
        for (int nt = 0; nt < 8; nt++)
          C[row*128 + nt*16 + lm] = f2b(acc[mt][nt][r]);
      }
    }
  }
}

// per-node dots from bf16 xp
__global__ void k_sdots(const unsigned* __restrict__ xb, const float* __restrict__ a_src,
                        const float* __restrict__ a_dst, float* __restrict__ ssrc,
                        float* __restrict__ sdst, int N){
  int n = blockIdx.x*4 + (threadIdx.x >> 6);
  int lane = threadIdx.x & 63;
  if (n >= N) return;
  unsigned w = xb[(size_t)n*64 + lane];
  float v0 = __uint_as_float(w << 16);
  float v1 = __uint_as_float(w & 0xFFFF0000u);
  float2 as = ((const float2*)a_src)[lane];
  float2 ad = ((const float2*)a_dst)[lane];
  float ps = v0*as.x + v1*as.y;
  float pd = v0*ad.x + v1*ad.y;
  #pragma unroll
  for (int off = 32; off >= 1; off >>= 1){
    ps += __shfl_xor(ps, off, 64);
    pd += __shfl_xor(pd, off, 64);
  }
  if (lane == 0){ ssrc[n] = ps; sdst[n] = pd; }
}

// ---------------- GAT aggregation: wave/node, 4 edges in flight (16 lanes each) ----------------
__global__ void k_gat(const ushort_t* __restrict__ xb, const int* __restrict__ rowp,
                      const int* __restrict__ col_src, const float* __restrict__ col_e,
                      const float* __restrict__ ssrc, const float* __restrict__ sdst,
                      const float* __restrict__ b_gat, ushort_t* __restrict__ hb,
                      float* __restrict__ y, int N){
  int n = blockIdx.x*4 + (threadIdx.x >> 6);
  int l = threadIdx.x & 63;
  if (n >= N) return;
  int rs = rowp[n], re = rowp[n+1];
  float es = ssrc[n] + sdst[n];
  es = (es >= 0.f) ? es : NEG_SLOPE*es;
  float m = es;
  for (int j = rs + l; j < re; j += 64) m = fmaxf(m, col_e[j]);
  #pragma unroll
  for (int off = 32; off >= 1; off >>= 1) m = fmaxf(m, __shfl_xor(m, off, 64));
  float s = 0.f;
  for (int j = rs + l; j < re; j += 64) s += __expf(col_e[j] - m);
  #pragma unroll
  for (int off = 32; off >= 1; off >>= 1) s += __shfl_xor(s, off, 64);
  s += __expf(es - m);
  float inv = 1.f / s;
  float a0 = __expf(es - m) * inv;

  int sub = l >> 4, q = l & 15;
  const uint4* x16 = (const uint4*)xb;
  float acc[8] = {0.f,0.f,0.f,0.f,0.f,0.f,0.f,0.f};
  int deg = re - rs;
  int iters = (deg + 3) >> 2;
  for (int i = 0; i < iters; i++){
    int edge = rs + (i << 2) + sub;
    float a = 0.f; int sidx = n;
    if (edge < re){ sidx = col_src[edge]; a = __expf(col_e[edge] - m) * inv; }
    uint4 v = x16[(size_t)sidx*16 + q];
    fma8(acc, v, a);
  }
  #pragma unroll
  for (int j = 0; j < 8; j++){
    acc[j] += __shfl_xor(acc[j], 16, 64);
    acc[j] += __shfl_xor(acc[j], 32, 64);
  }
  if (sub == 0){
    uint4 v = x16[(size_t)n*16 + q];
    fma8(acc, v, a0);
    float4 b0 = ((const float4*)b_gat)[q*2];
    float4 b1 = ((const float4*)b_gat)[q*2 + 1];
    acc[0]+=b0.x; acc[1]+=b0.y; acc[2]+=b0.z; acc[3]+=b0.w;
    acc[4]+=b1.x; acc[5]+=b1.y; acc[6]+=b1.z; acc[7]+=b1.w;
    ((uint4*)hb)[(size_t)n*16 + q] = pack8(acc);
    float4* y4 = (float4*)y;
    y4[(size_t)n*32 + q*2]     = make_float4(acc[0], acc[1], acc[2], acc[3]);
    y4[(size_t)n*32 + q*2 + 1] = make_float4(acc[4], acc[5], acc[6], acc[7]);
  }
}

// ---------------- GCN aggregation + ReLU + JK max ----------------
__global__ void k_gcn(const ushort_t* __restrict__ zb, const int* __restrict__ rowp,
                      const int* __restrict__ col_src, const float* __restrict__ col_norm,
                      const float* __restrict__ dinv, const float* __restrict__ bias,
                      ushort_t* __restrict__ hb, float* __restrict__ y, int N){
  int n = blockIdx.x*4 + (threadIdx.x >> 6);
  int l = threadIdx.x & 63;
  if (n >= N) return;
  int rs = rowp[n], re = rowp[n+1];
  float di = dinv[n];
  float sn = di * di;
  int sub = l >> 4, q = l & 15;
  const uint4* z16 = (const uint4*)zb;
  float acc[8] = {0.f,0.f,0.f,0.f,0.f,0.f,0.f,0.f};
  int deg = re - rs;
  int iters = (deg + 3) >> 2;
  for (int i = 0; i < iters; i++){
    int edge = rs + (i << 2) + sub;
    float a = 0.f; int sidx = n;
    if (edge < re){ sidx = col_src[edge]; a = col_norm[edge]; }
    uint4 v = z16[(size_t)sidx*16 + q];
    fma8(acc, v, a);
  }
  #pragma unroll
  for (int j = 0; j < 8; j++){
    acc[j] += __shfl_xor(acc[j], 16, 64);
    acc[j] += __shfl_xor(acc[j], 32, 64);
  }
  if (sub == 0){
    uint4 v = z16[(size_t)n*16 + q];
    fma8(acc, v, sn);
    float4 b0 = ((const float4*)bias)[q*2];
    float4 b1 = ((const float4*)bias)[q*2 + 1];
    acc[0]=fmaxf(acc[0]+b0.x,0.f); acc[1]=fmaxf(acc[1]+b0.y,0.f);
    acc[2]=fmaxf(acc[2]+b0.z,0.f); acc[3]=fmaxf(acc[3]+b0.w,0.f);
    acc[4]=fmaxf(acc[4]+b1.x,0.f); acc[5]=fmaxf(acc[5]+b1.y,0.f);
    acc[6]=fmaxf(acc[6]+b1.z,0.f); acc[7]=fmaxf(acc[7]+b1.w,0.f);
    ((uint4*)hb)[(size_t)n*16 + q] = pack8(acc);
    float4* y4 = (float4*)y;
    float4 y0 = y4[(size_t)n*32 + q*2];
    float4 y1 = y4[(size_t)n*32 + q*2 + 1];
    y0.x=fmaxf(y0.x,acc[0]); y0.y=fmaxf(y0.y,acc[1]); y0.z=fmaxf(y0.z,acc[2]); y0.w=fmaxf(y0.w,acc[3]);
    y1.x=fmaxf(y1.x,acc[4]); y1.y=fmaxf(y1.y,acc[5]); y1.z=fmaxf(y1.z,acc[6]); y1.w=fmaxf(y1.w,acc[7]);
    y4[(size_t)n*32 + q*2]     = y0;
    y4[(size_t)n*32 + q*2 + 1] = y1;
  }
}

extern "C" void kernel_launch(void* const* d_in, const int* in_sizes, int n_in,
                              void* d_out, int out_size, void* d_ws, size_t ws_size,
                              hipStream_t stream){
  const float* x      = (const float*)d_in[0];
  const int*   eidx   = (const int*)d_in[1];
  const float* emask  = (const float*)d_in[2];
  const float* W_gat  = (const float*)d_in[3];
  const float* a_src  = (const float*)d_in[4];
  const float* a_dst  = (const float*)d_in[5];
  const float* b_gat  = (const float*)d_in[6];
  const float* W_gcn  = (const float*)d_in[7];
  const float* b_gcn  = (const float*)d_in[8];
  int N = in_sizes[0] / HIDDEN;
  int E = in_sizes[1] / 2;
  const int* src = eidx;
  const int* dst = eidx + E;

  char* p = (char*)d_ws;
  auto carve = [&](size_t bytes)->char*{ char* q = p; p += align_up(bytes, 512); return q; };
  ushort_t* xb   = (ushort_t*)carve((size_t)N*HIDDEN*2);   // bf16 x
  ushort_t* zb   = (ushort_t*)carve((size_t)N*HIDDEN*2);   // bf16 xp / z
  ushort_t* hb   = (ushort_t*)carve((size_t)N*HIDDEN*2);   // bf16 h
  ushort_t* Wt   = (ushort_t*)carve((size_t)4*HIDDEN*HIDDEN*2);
  float* ssrc    = (float*)carve((size_t)N*4);
  float* sdst    = (float*)carve((size_t)N*4);
  float* dinv    = (float*)carve((size_t)N*4);
  int*   rowp    = (int*)  carve((size_t)(N+1)*4);
  int*   cursor  = (int*)  carve((size_t)N*4);
  int*   cnt     = (int*)  carve((size_t)N*4);
  int*   col_src = (int*)  carve((size_t)E*4);
  float* col_norm= (float*)carve((size_t)E*4);
  float* col_e   = (float*)carve((size_t)E*4);
  int nb = (N + 255) / 256;
  int*   blockSums = (int*)carve((size_t)nb*4);
  int*   blockOffs = (int*)carve((size_t)nb*4);
  (void)ws_size; (void)n_in; (void)out_size;

  hipMemsetAsync(cnt,  0, (size_t)N*4, stream);
  hipMemsetAsync(dinv, 0, (size_t)N*4, stream);

  int eb  = (E + 255) / 256;
  int gb  = (N + 127) / 128;               // 128 rows per MFMA gemm block
  int nwb = (N + 3) / 4;                   // 4 waves (nodes) per block
  long n2 = (long)N*64;
  int cb  = (int)((n2 + 255) / 256);

  k_hist  <<<eb, 256, 0, stream>>>(dst, emask, cnt, dinv, E);
  k_scan1 <<<nb, 256, 0, stream>>>(cnt, rowp, blockSums, N);
  k_scan2 <<<1,  256, 0, stream>>>(blockSums, blockOffs, nb);
  k_scan3 <<<nb, 256, 0, stream>>>(rowp, cnt, blockOffs, cursor, N, E);
  k_dinv  <<<nb, 256, 0, stream>>>(dinv, N);

  k_cast_x<<<cb, 256, 0, stream>>>(x, (unsigned*)xb, n2);
  k_cast_w<<<(4*HIDDEN*HIDDEN)/256, 256, 0, stream>>>(W_gat, W_gcn, Wt);

  k_gemm  <<<gb, 256, 0, stream>>>(xb, Wt, zb, N);                 // xp = x @ W_gat
  k_sdots <<<nwb,256, 0, stream>>>((const unsigned*)zb, a_src, a_dst, ssrc, sdst, N);
  k_scatter<<<eb,256, 0, stream>>>(src, dst, emask, ssrc, sdst, dinv,
                                   cursor, col_src, col_norm, col_e, E);
  k_gat   <<<nwb,256, 0, stream>>>(zb, rowp, col_src, col_e, ssrc, sdst,
                                   b_gat, hb, (float*)d_out, N);

  for (int l = 0; l < 3; l++){
    k_gemm<<<gb, 256, 0, stream>>>(hb, Wt + (size_t)(l+1)*HIDDEN*HIDDEN, zb, N);
    k_gcn <<<nwb,256, 0, stream>>>(zb, rowp, col_src, col_norm, dinv,
                                   b_gcn + (size_t)l*HIDDEN, hb, (float*)d_out, N);
  }
}

// Round 3
// 458.877 us; speedup vs baseline: 1.7229x; 1.0413x over previous
//
#include <hip/hip_runtime.h>

#define HIDDEN 128
#define NEG_SLOPE 0.2f
#define NB_SORT 64          // blocks for counting-sort phases
#define NH_MAX 25000        // (N+1)/2 for N=50000, u32 words of packed u16 counters

typedef unsigned short ushort_t;
typedef __attribute__((ext_vector_type(8))) short short8;
typedef __attribute__((ext_vector_type(4))) float floatx4;

static inline size_t align_up(size_t x, size_t a){ return (x + a - 1) & ~(a - 1); }

__device__ __forceinline__ ushort_t f2b(float f){
  unsigned u = __float_as_uint(f);
  unsigned r = (u + 0x7FFFu + ((u >> 16) & 1u)) >> 16;
  return (ushort_t)r;
}

__device__ __forceinline__ void fma8(float* acc, uint4 v, float a){
  acc[0] += a * __uint_as_float(v.x << 16);
  acc[1] += a * __uint_as_float(v.x & 0xFFFF0000u);
  acc[2] += a * __uint_as_float(v.y << 16);
  acc[3] += a * __uint_as_float(v.y & 0xFFFF0000u);
  acc[4] += a * __uint_as_float(v.z << 16);
  acc[5] += a * __uint_as_float(v.z & 0xFFFF0000u);
  acc[6] += a * __uint_as_float(v.w << 16);
  acc[7] += a * __uint_as_float(v.w & 0xFFFF0000u);
}

__device__ __forceinline__ uint4 pack8(const float* f){
  uint4 u;
  u.x = (unsigned)f2b(f[0]) | ((unsigned)f2b(f[1]) << 16);
  u.y = (unsigned)f2b(f[2]) | ((unsigned)f2b(f[3]) << 16);
  u.z = (unsigned)f2b(f[4]) | ((unsigned)f2b(f[5]) << 16);
  u.w = (unsigned)f2b(f[6]) | ((unsigned)f2b(f[7]) << 16);
  return u;
}

// ---------------- CSR build: LDS-privatized counting sort (no global atomics) ----------------

// Phase 1: per-block histogram into packed u16-pair LDS counters; write partial row.
__global__ __launch_bounds__(256) void k_cnt(const int* __restrict__ dst,
                                             unsigned* __restrict__ histw,
                                             int E, int epb, int nh){
  __shared__ unsigned lds[NH_MAX];
  int t = threadIdx.x;
  for (int i = t; i < nh; i += 256) lds[i] = 0;
  __syncthreads();
  int e0 = blockIdx.x * epb;
  int e1 = min(E, e0 + epb);
  for (int e = e0 + t; e < e1; e += 256){
    int d = dst[e];
    atomicAdd(&lds[d >> 1], 1u << ((d & 1) * 16));
  }
  __syncthreads();
  size_t base = (size_t)blockIdx.x * nh;
  for (int i = t; i < nh; i += 256) histw[base + i] = lds[i];
}

// Phase 2: in-place exclusive scan across block-rows (per packed half), emit totals.
// Each thread owns 4 consecutive u32 words (uint4 loads, 4 independent chains).
__global__ void k_merge(unsigned* __restrict__ histw, int* __restrict__ cnt,
                        int nh4, int nh, int nblk, int N){
  int t = blockIdx.x*256 + threadIdx.x;
  if (t >= nh4) return;
  unsigned a0=0,a1=0,b0=0,b1=0,c0=0,c1=0,d0=0,d1=0;
  for (int b = 0; b < nblk; b++){
    uint4* p = (uint4*)(histw + (size_t)b*nh) + t;
    uint4 v = *p;
    uint4 w;
    w.x = a0 | (a1 << 16); w.y = b0 | (b1 << 16);
    w.z = c0 | (c1 << 16); w.w = d0 | (d1 << 16);
    *p = w;
    a0 += v.x & 0xFFFFu; a1 += v.x >> 16;
    b0 += v.y & 0xFFFFu; b1 += v.y >> 16;
    c0 += v.z & 0xFFFFu; c1 += v.z >> 16;
    d0 += v.w & 0xFFFFu; d1 += v.w >> 16;
  }
  int i = t*8;
  unsigned tot[8] = {a0,a1,b0,b1,c0,c1,d0,d1};
  #pragma unroll
  for (int j = 0; j < 8; j++) if (i + j < N) cnt[i + j] = (int)tot[j];
}

// scans (verified round 1)
__global__ void k_scan1(const int* __restrict__ cnt, int* __restrict__ incl,
                        int* __restrict__ blockSums, int N){
  __shared__ int sd[256];
  int t = threadIdx.x;
  int i = blockIdx.x*256 + t;
  int v = (i < N) ? cnt[i] : 0;
  sd[t] = v; __syncthreads();
  for (int off = 1; off < 256; off <<= 1){
    int add = (t >= off) ? sd[t-off] : 0;
    __syncthreads();
    sd[t] += add;
    __syncthreads();
  }
  if (i < N) incl[i] = sd[t];
  if (t == 255) blockSums[blockIdx.x] = sd[255];
}

__global__ void k_scan2(const int* __restrict__ blockSums, int* __restrict__ blockOffs, int nb){
  __shared__ int sd[256];
  __shared__ int carry;
  int t = threadIdx.x;
  if (t == 0) carry = 0;
  __syncthreads();
  for (int base = 0; base < nb; base += 256){
    int i = base + t;
    int v = (i < nb) ? blockSums[i] : 0;
    sd[t] = v; __syncthreads();
    for (int off = 1; off < 256; off <<= 1){
      int add = (t >= off) ? sd[t-off] : 0;
      __syncthreads();
      sd[t] += add;
      __syncthreads();
    }
    if (i < nb) blockOffs[i] = carry + sd[t] - v;
    __syncthreads();
    if (t == 0) carry += sd[255];
    __syncthreads();
  }
}

__global__ void k_scan3(int* __restrict__ rowp, const int* __restrict__ cnt,
                        const int* __restrict__ blockOffs, int N, int E){
  int i = blockIdx.x*256 + threadIdx.x;
  if (i < N){
    int excl = rowp[i] - cnt[i] + blockOffs[blockIdx.x];
    rowp[i] = excl;
  }
  if (i == 0) rowp[N] = E;
}

// Phase 3: replay edges, LDS rank + scanned base -> deterministic-slot scatter (no global atomics)
__global__ __launch_bounds__(256) void k_place(const int* __restrict__ src,
                                               const int* __restrict__ dst,
                                               const float* __restrict__ w,
                                               const unsigned* __restrict__ histw,
                                               const int* __restrict__ rowp,
                                               int* __restrict__ col_src,
                                               float* __restrict__ col_w,
                                               int E, int epb, int nh){
  __shared__ unsigned lds[NH_MAX];
  int t = threadIdx.x;
  for (int i = t; i < nh; i += 256) lds[i] = 0;
  __syncthreads();
  size_t hbase = (size_t)blockIdx.x * nh;
  int e0 = blockIdx.x * epb;
  int e1 = min(E, e0 + epb);
  for (int e = e0 + t; e < e1; e += 256){
    int d = dst[e];
    int sh = (d & 1) * 16;
    unsigned old = atomicAdd(&lds[d >> 1], 1u << sh);
    unsigned rank = (old >> sh) & 0xFFFFu;
    unsigned base = (histw[hbase + (d >> 1)] >> sh) & 0xFFFFu;
    int pos = rowp[d] + (int)base + (int)rank;
    col_src[pos] = src[e];
    col_w[pos]   = w[e];
  }
}

// per-node weighted degree -> dinv (16 lanes per node)
__global__ void k_deg(const int* __restrict__ rowp, const float* __restrict__ col_w,
                      float* __restrict__ dinv, int N){
  int n = blockIdx.x*16 + (threadIdx.x >> 4);
  int l = threadIdx.x & 15;
  if (n >= N) return;
  int rs = rowp[n], re = rowp[n+1];
  float s = 0.f;
  for (int j = rs + l; j < re; j += 16) s += col_w[j];
  s += __shfl_xor(s, 1); s += __shfl_xor(s, 2);
  s += __shfl_xor(s, 4); s += __shfl_xor(s, 8);
  if (l == 0) dinv[n] = rsqrtf(s + 1.0f);   // +1 = self-loop weight
}

// per-edge GCN norm + GAT logit from CSR (16 lanes per node)
__global__ void k_edges(const int* __restrict__ rowp, const int* __restrict__ col_src,
                        const float* __restrict__ col_w, const float* __restrict__ dinv,
                        const float* __restrict__ ssrc, const float* __restrict__ sdst,
                        float* __restrict__ col_norm, float* __restrict__ col_e, int N){
  int n = blockIdx.x*16 + (threadIdx.x >> 4);
  int l = threadIdx.x & 15;
  if (n >= N) return;
  int rs = rowp[n], re = rowp[n+1];
  float dn = dinv[n], sd = sdst[n];
  for (int j = rs + l; j < re; j += 16){
    int s = col_src[j];
    col_norm[j] = dinv[s] * col_w[j] * dn;
    float ee = ssrc[s] + sd;
    col_e[j] = (ee >= 0.f) ? ee : NEG_SLOPE*ee;
  }
}

// ---------------- casts ----------------

__global__ void k_cast_x(const float* __restrict__ x, unsigned* __restrict__ xb, long n2){
  long i = (long)blockIdx.x*256 + threadIdx.x;
  if (i >= n2) return;
  float2 v = ((const float2*)x)[i];
  xb[i] = (unsigned)f2b(v.x) | ((unsigned)f2b(v.y) << 16);
}

__global__ void k_cast_w(const float* __restrict__ Wg, const float* __restrict__ Wc,
                         ushort_t* __restrict__ Wt){
  int i = blockIdx.x*256 + threadIdx.x;       // 4*16384
  int mat = i >> 14, idx = i & 16383;
  int k = idx >> 7, n = idx & 127;
  float v = (mat == 0) ? Wg[idx] : Wc[(mat-1)*16384 + idx];
  Wt[mat*16384 + n*128 + k] = f2b(v);
}

// ---------------- MFMA GEMM (verified round 2) ----------------
__global__ __launch_bounds__(256) void k_gemm(const ushort_t* __restrict__ A,
                                              const ushort_t* __restrict__ Wt,
                                              ushort_t* __restrict__ C, int M){
  int wave = threadIdx.x >> 6, l = threadIdx.x & 63;
  int q = l >> 4, lm = l & 15;
  int rowBase = blockIdx.x*128 + wave*32;
  floatx4 acc[2][8];
  #pragma unroll
  for (int mt = 0; mt < 2; mt++)
    #pragma unroll
    for (int nt = 0; nt < 8; nt++) acc[mt][nt] = (floatx4){0.f,0.f,0.f,0.f};

  #pragma unroll
  for (int kc = 0; kc < 4; kc++){
    int k0 = kc*32 + q*8;
    short8 a[2];
    #pragma unroll
    for (int mt = 0; mt < 2; mt++){
      long r = rowBase + mt*16 + lm;
      if (r < M) a[mt] = *(const short8*)(A + r*128 + k0);
      else       a[mt] = (short8){0,0,0,0,0,0,0,0};
    }
    #pragma unroll
    for (int nt = 0; nt < 8; nt++){
      short8 b = *(const short8*)(Wt + (nt*16 + lm)*128 + k0);
      acc[0][nt] = __builtin_amdgcn_mfma_f32_16x16x32_bf16(a[0], b, acc[0][nt], 0, 0, 0);
      acc[1][nt] = __builtin_amdgcn_mfma_f32_16x16x32_bf16(a[1], b, acc[1][nt], 0, 0, 0);
    }
  }
  #pragma unroll
  for (int mt = 0; mt < 2; mt++){
    #pragma unroll
    for (int r = 0; r < 4; r++){
      long row = rowBase + mt*16 + q*4 + r;
      if (row < M){
        #pragma unroll
        for (int nt = 0; nt < 8; nt++)
          C[row*128 + nt*16 + lm] = f2b(acc[mt][nt][r]);
      }
    }
  }
}

__global__ void k_sdots(const unsigned* __restrict__ xb, const float* __restrict__ a_src,
                        const float* __restrict__ a_dst, float* __restrict__ ssrc,
                        float* __restrict__ sdst, int N){
  int n = blockIdx.x*4 + (threadIdx.x >> 6);
  int lane = threadIdx.x & 63;
  if (n >= N) return;
  unsigned w = xb[(size_t)n*64 + lane];
  float v0 = __uint_as_float(w << 16);
  float v1 = __uint_as_float(w & 0xFFFF0000u);
  float2 as = ((const float2*)a_src)[lane];
  float2 ad = ((const float2*)a_dst)[lane];
  float ps = v0*as.x + v1*as.y;
  float pd = v0*ad.x + v1*ad.y;
  #pragma unroll
  for (int off = 32; off >= 1; off >>= 1){
    ps += __shfl_xor(ps, off, 64);
    pd += __shfl_xor(pd, off, 64);
  }
  if (lane == 0){ ssrc[n] = ps; sdst[n] = pd; }
}

// ---------------- GAT aggregation (verified round 2) ----------------
__global__ void k_gat(const ushort_t* __restrict__ xb, const int* __restrict__ rowp,
                      const int* __restrict__ col_src, const float* __restrict__ col_e,
                      const float* __restrict__ ssrc, const float* __restrict__ sdst,
                      const float* __restrict__ b_gat, ushort_t* __restrict__ hb,
                      float* __restrict__ y, int N){
  int n = blockIdx.x*4 + (threadIdx.x >> 6);
  int l = threadIdx.x & 63;
  if (n >= N) return;
  int rs = rowp[n], re = rowp[n+1];
  float es = ssrc[n] + sdst[n];
  es = (es >= 0.f) ? es : NEG_SLOPE*es;
  float m = es;
  for (int j = rs + l; j < re; j += 64) m = fmaxf(m, col_e[j]);
  #pragma unroll
  for (int off = 32; off >= 1; off >>= 1) m = fmaxf(m, __shfl_xor(m, off, 64));
  float s = 0.f;
  for (int j = rs + l; j < re; j += 64) s += __expf(col_e[j] - m);
  #pragma unroll
  for (int off = 32; off >= 1; off >>= 1) s += __shfl_xor(s, off, 64);
  s += __expf(es - m);
  float inv = 1.f / s;
  float a0 = __expf(es - m) * inv;

  int sub = l >> 4, q = l & 15;
  const uint4* x16 = (const uint4*)xb;
  float acc[8] = {0.f,0.f,0.f,0.f,0.f,0.f,0.f,0.f};
  int deg = re - rs;
  int iters = (deg + 3) >> 2;
  for (int i = 0; i < iters; i++){
    int edge = rs + (i << 2) + sub;
    float a = 0.f; int sidx = n;
    if (edge < re){ sidx = col_src[edge]; a = __expf(col_e[edge] - m) * inv; }
    uint4 v = x16[(size_t)sidx*16 + q];
    fma8(acc, v, a);
  }
  #pragma unroll
  for (int j = 0; j < 8; j++){
    acc[j] += __shfl_xor(acc[j], 16, 64);
    acc[j] += __shfl_xor(acc[j], 32, 64);
  }
  if (sub == 0){
    uint4 v = x16[(size_t)n*16 + q];
    fma8(acc, v, a0);
    float4 b0 = ((const float4*)b_gat)[q*2];
    float4 b1 = ((const float4*)b_gat)[q*2 + 1];
    acc[0]+=b0.x; acc[1]+=b0.y; acc[2]+=b0.z; acc[3]+=b0.w;
    acc[4]+=b1.x; acc[5]+=b1.y; acc[6]+=b1.z; acc[7]+=b1.w;
    ((uint4*)hb)[(size_t)n*16 + q] = pack8(acc);
    float4* y4 = (float4*)y;
    y4[(size_t)n*32 + q*2]     = make_float4(acc[0], acc[1], acc[2], acc[3]);
    y4[(size_t)n*32 + q*2 + 1] = make_float4(acc[4], acc[5], acc[6], acc[7]);
  }
}

// ---------------- GCN aggregation + ReLU + JK max (verified round 2) ----------------
__global__ void k_gcn(const ushort_t* __restrict__ zb, const int* __restrict__ rowp,
                      const int* __restrict__ col_src, const float* __restrict__ col_norm,
                      const float* __restrict__ dinv, const float* __restrict__ bias,
                      ushort_t* __restrict__ hb, float* __restrict__ y, int N){
  int n = blockIdx.x*4 + (threadIdx.x >> 6);
  int l = threadIdx.x & 63;
  if (n >= N) return;
  int rs = rowp[n], re = rowp[n+1];
  float di = dinv[n];
  float sn = di * di;
  int sub = l >> 4, q = l & 15;
  const uint4* z16 = (const uint4*)zb;
  float acc[8] = {0.f,0.f,0.f,0.f,0.f,0.f,0.f,0.f};
  int deg = re - rs;
  int iters = (deg + 3) >> 2;
  for (int i = 0; i < iters; i++){
    int edge = rs + (i << 2) + sub;
    float a = 0.f; int sidx = n;
    if (edge < re){ sidx = col_src[edge]; a = col_norm[edge]; }
    uint4 v = z16[(size_t)sidx*16 + q];
    fma8(acc, v, a);
  }
  #pragma unroll
  for (int j = 0; j < 8; j++){
    acc[j] += __shfl_xor(acc[j], 16, 64);
    acc[j] += __shfl_xor(acc[j], 32, 64);
  }
  if (sub == 0){
    uint4 v = z16[(size_t)n*16 + q];
    fma8(acc, v, sn);
    float4 b0 = ((const float4*)bias)[q*2];
    float4 b1 = ((const float4*)bias)[q*2 + 1];
    acc[0]=fmaxf(acc[0]+b0.x,0.f); acc[1]=fmaxf(acc[1]+b0.y,0.f);
    acc[2]=fmaxf(acc[2]+b0.z,0.f); acc[3]=fmaxf(acc[3]+b0.w,0.f);
    acc[4]=fmaxf(acc[4]+b1.x,0.f); acc[5]=fmaxf(acc[5]+b1.y,0.f);
    acc[6]=fmaxf(acc[6]+b1.z,0.f); acc[7]=fmaxf(acc[7]+b1.w,0.f);
    ((uint4*)hb)[(size_t)n*16 + q] = pack8(acc);
    float4* y4 = (float4*)y;
    float4 y0 = y4[(size_t)n*32 + q*2];
    float4 y1 = y4[(size_t)n*32 + q*2 + 1];
    y0.x=fmaxf(y0.x,acc[0]); y0.y=fmaxf(y0.y,acc[1]); y0.z=fmaxf(y0.z,acc[2]); y0.w=fmaxf(y0.w,acc[3]);
    y1.x=fmaxf(y1.x,acc[4]); y1.y=fmaxf(y1.y,acc[5]); y1.z=fmaxf(y1.z,acc[6]); y1.w=fmaxf(y1.w,acc[7]);
    y4[(size_t)n*32 + q*2]     = y0;
    y4[(size_t)n*32 + q*2 + 1] = y1;
  }
}

extern "C" void kernel_launch(void* const* d_in, const int* in_sizes, int n_in,
                              void* d_out, int out_size, void* d_ws, size_t ws_size,
                              hipStream_t stream){
  const float* x      = (const float*)d_in[0];
  const int*   eidx   = (const int*)d_in[1];
  const float* emask  = (const float*)d_in[2];
  const float* W_gat  = (const float*)d_in[3];
  const float* a_src  = (const float*)d_in[4];
  const float* a_dst  = (const float*)d_in[5];
  const float* b_gat  = (const float*)d_in[6];
  const float* W_gcn  = (const float*)d_in[7];
  const float* b_gcn  = (const float*)d_in[8];
  int N = in_sizes[0] / HIDDEN;
  int E = in_sizes[1] / 2;
  const int* src = eidx;
  const int* dst = eidx + E;

  char* p = (char*)d_ws;
  auto carve = [&](size_t bytes)->char*{ char* q = p; p += align_up(bytes, 512); return q; };
  ushort_t* xb   = (ushort_t*)carve((size_t)N*HIDDEN*2);
  ushort_t* zb   = (ushort_t*)carve((size_t)N*HIDDEN*2);
  ushort_t* hb   = (ushort_t*)carve((size_t)N*HIDDEN*2);
  ushort_t* Wt   = (ushort_t*)carve((size_t)4*HIDDEN*HIDDEN*2);
  float* ssrc    = (float*)carve((size_t)N*4);
  float* sdst    = (float*)carve((size_t)N*4);
  float* dinv    = (float*)carve((size_t)N*4);
  int*   rowp    = (int*)  carve((size_t)(N+1)*4);
  int*   cnt     = (int*)  carve((size_t)N*4);
  int*   col_src = (int*)  carve((size_t)E*4);
  float* col_w   = (float*)carve((size_t)E*4);
  float* col_norm= (float*)carve((size_t)E*4);
  float* col_e   = (float*)carve((size_t)E*4);
  int nh = (N + 1) >> 1;                       // packed u16-pair words
  unsigned* histw = (unsigned*)carve((size_t)NB_SORT*nh*4);
  int nb = (N + 255) / 256;
  int*   blockSums = (int*)carve((size_t)nb*4);
  int*   blockOffs = (int*)carve((size_t)nb*4);
  (void)ws_size; (void)n_in; (void)out_size;

  int epb = (E + NB_SORT - 1) / NB_SORT;
  int nh4 = nh / 4;                            // 25000/4 = 6250
  int gb  = (N + 127) / 128;
  int nwb = (N + 3) / 4;
  int nqb = (N + 15) / 16;
  long n2 = (long)N*64;
  int cb  = (int)((n2 + 255) / 256);

  // CSR build (atomic-free)
  k_cnt  <<<NB_SORT, 256, 0, stream>>>(dst, histw, E, epb, nh);
  k_merge<<<(nh4 + 255)/256, 256, 0, stream>>>(histw, cnt, nh4, nh, NB_SORT, N);
  k_scan1<<<nb, 256, 0, stream>>>(cnt, rowp, blockSums, N);
  k_scan2<<<1,  256, 0, stream>>>(blockSums, blockOffs, nb);
  k_scan3<<<nb, 256, 0, stream>>>(rowp, cnt, blockOffs, N, E);
  k_place<<<NB_SORT, 256, 0, stream>>>(src, dst, emask, histw, rowp, col_src, col_w, E, epb, nh);

  // features
  k_cast_x<<<cb, 256, 0, stream>>>(x, (unsigned*)xb, n2);
  k_cast_w<<<(4*HIDDEN*HIDDEN)/256, 256, 0, stream>>>(W_gat, W_gcn, Wt);

  k_gemm <<<gb, 256, 0, stream>>>(xb, Wt, zb, N);                 // xp = x @ W_gat
  k_sdots<<<nwb,256, 0, stream>>>((const unsigned*)zb, a_src, a_dst, ssrc, sdst, N);
  k_deg  <<<nqb,256, 0, stream>>>(rowp, col_w, dinv, N);
  k_edges<<<nqb,256, 0, stream>>>(rowp, col_src, col_w, dinv, ssrc, sdst, col_norm, col_e, N);

  k_gat  <<<nwb,256, 0, stream>>>(zb, rowp, col_src, col_e, ssrc, sdst,
                                  b_gat, hb, (float*)d_out, N);
  for (int l = 0; l < 3; l++){
    k_gemm<<<gb, 256, 0, stream>>>(hb, Wt + (size_t)(l+1)*HIDDEN*HIDDEN, zb, N);
    k_gcn <<<nqb*4,256, 0, stream>>>(zb, rowp, col_src, col_norm, dinv,
                                     b_gcn + (size_t)l*HIDDEN, hb, (float*)d_out, N);
  }
}

// Round 4
// 393.933 us; speedup vs baseline: 2.0070x; 1.1649x over previous
//
#include <hip/hip_runtime.h>

#define HIDDEN 128
#define NEG_SLOPE 0.2f
#define P_SORT 256          // blocks for phase-1 bucket sort

typedef unsigned short ushort_t;
typedef __attribute__((ext_vector_type(8))) short short8;
typedef __attribute__((ext_vector_type(4))) float floatx4;

static inline size_t align_up(size_t x, size_t a){ return (x + a - 1) & ~(a - 1); }

__device__ __forceinline__ ushort_t f2b(float f){
  unsigned u = __float_as_uint(f);
  unsigned r = (u + 0x7FFFu + ((u >> 16) & 1u)) >> 16;
  return (ushort_t)r;
}

__device__ __forceinline__ void fma8(float* acc, uint4 v, float a){
  acc[0] += a * __uint_as_float(v.x << 16);
  acc[1] += a * __uint_as_float(v.x & 0xFFFF0000u);
  acc[2] += a * __uint_as_float(v.y << 16);
  acc[3] += a * __uint_as_float(v.y & 0xFFFF0000u);
  acc[4] += a * __uint_as_float(v.z << 16);
  acc[5] += a * __uint_as_float(v.z & 0xFFFF0000u);
  acc[6] += a * __uint_as_float(v.w << 16);
  acc[7] += a * __uint_as_float(v.w & 0xFFFF0000u);
}

__device__ __forceinline__ uint4 pack8(const float* f){
  uint4 u;
  u.x = (unsigned)f2b(f[0]) | ((unsigned)f2b(f[1]) << 16);
  u.y = (unsigned)f2b(f[2]) | ((unsigned)f2b(f[3]) << 16);
  u.z = (unsigned)f2b(f[4]) | ((unsigned)f2b(f[5]) << 16);
  u.w = (unsigned)f2b(f[6]) | ((unsigned)f2b(f[7]) << 16);
  return u;
}

// ============ CSR build: two-pass bucketed counting sort (no global atomics) ============

// Phase 1a: per-block coarse histogram (bucket = dst>>8), 1KB LDS, bucket-major output.
__global__ __launch_bounds__(256) void k_b1cnt(const int* __restrict__ dst,
                                               int* __restrict__ bcnt,
                                               int E, int epb, int nbkt){
  __shared__ unsigned c[256];
  int t = threadIdx.x;
  c[t] = 0;
  __syncthreads();
  int e0 = blockIdx.x * epb;
  int e1 = min(E, e0 + epb);
  for (int e = e0 + t; e < e1; e += 256) atomicAdd(&c[dst[e] >> 8], 1u);
  __syncthreads();
  if (t < nbkt) bcnt[t * P_SORT + blockIdx.x] = (int)c[t];
}

// generic scans (ladder verified round 1)
__global__ void k_scan1(const int* __restrict__ in, int* __restrict__ incl,
                        int* __restrict__ blockSums, int M){
  __shared__ int sd[256];
  int t = threadIdx.x;
  int i = blockIdx.x*256 + t;
  int v = (i < M) ? in[i] : 0;
  sd[t] = v; __syncthreads();
  for (int off = 1; off < 256; off <<= 1){
    int add = (t >= off) ? sd[t-off] : 0;
    __syncthreads();
    sd[t] += add;
    __syncthreads();
  }
  if (i < M) incl[i] = sd[t];
  if (t == 255) blockSums[blockIdx.x] = sd[255];
}

__global__ void k_scan2(const int* __restrict__ blockSums, int* __restrict__ blockOffs, int nb){
  __shared__ int sd[256];
  __shared__ int carry;
  int t = threadIdx.x;
  if (t == 0) carry = 0;
  __syncthreads();
  for (int base = 0; base < nb; base += 256){
    int i = base + t;
    int v = (i < nb) ? blockSums[i] : 0;
    sd[t] = v; __syncthreads();
    for (int off = 1; off < 256; off <<= 1){
      int add = (t >= off) ? sd[t-off] : 0;
      __syncthreads();
      sd[t] += add;
      __syncthreads();
    }
    if (i < nb) blockOffs[i] = carry + sd[t] - v;
    __syncthreads();
    if (t == 0) carry += sd[255];
    __syncthreads();
  }
}

// inclusive -> exclusive, in place
__global__ void k_scanex(int* __restrict__ arr, const int* __restrict__ in,
                         const int* __restrict__ blockOffs, int M){
  int i = blockIdx.x*256 + threadIdx.x;
  if (i < M) arr[i] = arr[i] - in[i] + blockOffs[blockIdx.x];
}

// Phase 1b: replay edges, LDS rank within (block,bucket), write packed records.
__global__ __launch_bounds__(256) void k_b1place(const int* __restrict__ src,
                                                 const int* __restrict__ dst,
                                                 const float* __restrict__ w,
                                                 const int* __restrict__ ebase,
                                                 unsigned* __restrict__ tpk,
                                                 float* __restrict__ tw,
                                                 int E, int epb){
  __shared__ unsigned c[256];
  int t = threadIdx.x;
  c[t] = 0;
  __syncthreads();
  int e0 = blockIdx.x * epb;
  int e1 = min(E, e0 + epb);
  for (int e = e0 + t; e < e1; e += 256){
    int d = dst[e];
    int b = d >> 8;
    unsigned r = atomicAdd(&c[b], 1u);
    int pos = ebase[b * P_SORT + blockIdx.x] + (int)r;
    tpk[pos] = (unsigned)src[e] | ((unsigned)(d & 255) << 16);   // src < 65536
    tw[pos]  = w[e];
  }
}

// Phase 2: per-bucket fine sort (256 dst values), writes rowp, col_src, col_w, dinv.
__global__ __launch_bounds__(256) void k_b2(const unsigned* __restrict__ tpk,
                                            const float* __restrict__ tw,
                                            const int* __restrict__ ebase,
                                            int* __restrict__ col_src,
                                            float* __restrict__ col_w,
                                            int* __restrict__ rowp,
                                            float* __restrict__ dinv,
                                            int N, int E, int nbkt){
  __shared__ unsigned hcnt[256];
  __shared__ int sd[256];
  __shared__ int lofs[256];
  __shared__ unsigned rcnt[256];
  __shared__ float wsum[256];
  int b = blockIdx.x, t = threadIdx.x;
  int e0 = ebase[b * P_SORT];
  int e1 = (b + 1 < nbkt) ? ebase[(b + 1) * P_SORT] : E;
  hcnt[t] = 0; rcnt[t] = 0; wsum[t] = 0.f;
  __syncthreads();
  for (int e = e0 + t; e < e1; e += 256) atomicAdd(&hcnt[(tpk[e] >> 16) & 255u], 1u);
  __syncthreads();
  int v = (int)hcnt[t];
  sd[t] = v; __syncthreads();
  for (int off = 1; off < 256; off <<= 1){
    int add = (t >= off) ? sd[t-off] : 0;
    __syncthreads();
    sd[t] += add;
    __syncthreads();
  }
  lofs[t] = sd[t] - v;
  int node = b*256 + t;
  if (node < N) rowp[node] = e0 + sd[t] - v;
  if (b == 0 && t == 0) rowp[N] = E;
  __syncthreads();
  for (int e = e0 + t; e < e1; e += 256){
    unsigned pk = tpk[e];
    float wv = tw[e];
    unsigned dl = (pk >> 16) & 255u;
    unsigned r = atomicAdd(&rcnt[dl], 1u);
    int pos = e0 + lofs[dl] + (int)r;
    col_src[pos] = (int)(pk & 0xFFFFu);
    col_w[pos]   = wv;
    atomicAdd(&wsum[dl], wv);
  }
  __syncthreads();
  if (node < N) dinv[node] = rsqrtf(wsum[t] + 1.0f);   // +1 = self-loop weight
}

// per-edge GCN norm + GAT logit from CSR (16 lanes per node)
__global__ void k_edges(const int* __restrict__ rowp, const int* __restrict__ col_src,
                        const float* __restrict__ col_w, const float* __restrict__ dinv,
                        const float* __restrict__ ssrc, const float* __restrict__ sdst,
                        float* __restrict__ col_norm, float* __restrict__ col_e, int N){
  int n = blockIdx.x*16 + (threadIdx.x >> 4);
  int l = threadIdx.x & 15;
  if (n >= N) return;
  int rs = rowp[n], re = rowp[n+1];
  float dn = dinv[n], sd = sdst[n];
  for (int j = rs + l; j < re; j += 16){
    int s = col_src[j];
    col_norm[j] = dinv[s] * col_w[j] * dn;
    float ee = ssrc[s] + sd;
    col_e[j] = (ee >= 0.f) ? ee : NEG_SLOPE*ee;
  }
}

// ---------------- casts ----------------

__global__ void k_cast_x(const float* __restrict__ x, unsigned* __restrict__ xb, long n2){
  long i = (long)blockIdx.x*256 + threadIdx.x;
  if (i >= n2) return;
  float2 v = ((const float2*)x)[i];
  xb[i] = (unsigned)f2b(v.x) | ((unsigned)f2b(v.y) << 16);
}

__global__ void k_cast_w(const float* __restrict__ Wg, const float* __restrict__ Wc,
                         ushort_t* __restrict__ Wt){
  int i = blockIdx.x*256 + threadIdx.x;       // 4*16384
  int mat = i >> 14, idx = i & 16383;
  int k = idx >> 7, n = idx & 127;
  float v = (mat == 0) ? Wg[idx] : Wc[(mat-1)*16384 + idx];
  Wt[mat*16384 + n*128 + k] = f2b(v);
}

// ---------------- MFMA GEMM (verified round 2) ----------------
__global__ __launch_bounds__(256) void k_gemm(const ushort_t* __restrict__ A,
                                              const ushort_t* __restrict__ Wt,
                                              ushort_t* __restrict__ C, int M){
  int wave = threadIdx.x >> 6, l = threadIdx.x & 63;
  int q = l >> 4, lm = l & 15;
  int rowBase = blockIdx.x*128 + wave*32;
  floatx4 acc[2][8];
  #pragma unroll
  for (int mt = 0; mt < 2; mt++)
    #pragma unroll
    for (int nt = 0; nt < 8; nt++) acc[mt][nt] = (floatx4){0.f,0.f,0.f,0.f};

  #pragma unroll
  for (int kc = 0; kc < 4; kc++){
    int k0 = kc*32 + q*8;
    short8 a[2];
    #pragma unroll
    for (int mt = 0; mt < 2; mt++){
      long r = rowBase + mt*16 + lm;
      if (r < M) a[mt] = *(const short8*)(A + r*128 + k0);
      else       a[mt] = (short8){0,0,0,0,0,0,0,0};
    }
    #pragma unroll
    for (int nt = 0; nt < 8; nt++){
      short8 b = *(const short8*)(Wt + (nt*16 + lm)*128 + k0);
      acc[0][nt] = __builtin_amdgcn_mfma_f32_16x16x32_bf16(a[0], b, acc[0][nt], 0, 0, 0);
      acc[1][nt] = __builtin_amdgcn_mfma_f32_16x16x32_bf16(a[1], b, acc[1][nt], 0, 0, 0);
    }
  }
  #pragma unroll
  for (int mt = 0; mt < 2; mt++){
    #pragma unroll
    for (int r = 0; r < 4; r++){
      long row = rowBase + mt*16 + q*4 + r;
      if (row < M){
        #pragma unroll
        for (int nt = 0; nt < 8; nt++)
          C[row*128 + nt*16 + lm] = f2b(acc[mt][nt][r]);
      }
    }
  }
}

__global__ void k_sdots(const unsigned* __restrict__ xb, const float* __restrict__ a_src,
                        const float* __restrict__ a_dst, float* __restrict__ ssrc,
                        float* __restrict__ sdst, int N){
  int n = blockIdx.x*4 + (threadIdx.x >> 6);
  int lane = threadIdx.x & 63;
  if (n >= N) return;
  unsigned w = xb[(size_t)n*64 + lane];
  float v0 = __uint_as_float(w << 16);
  float v1 = __uint_as_float(w & 0xFFFF0000u);
  float2 as = ((const float2*)a_src)[lane];
  float2 ad = ((const float2*)a_dst)[lane];
  float ps = v0*as.x + v1*as.y;
  float pd = v0*ad.x + v1*ad.y;
  #pragma unroll
  for (int off = 32; off >= 1; off >>= 1){
    ps += __shfl_xor(ps, off, 64);
    pd += __shfl_xor(pd, off, 64);
  }
  if (lane == 0){ ssrc[n] = ps; sdst[n] = pd; }
}

// ---------------- GAT aggregation (verified round 2) ----------------
__global__ void k_gat(const ushort_t* __restrict__ xb, const int* __restrict__ rowp,
                      const int* __restrict__ col_src, const float* __restrict__ col_e,
                      const float* __restrict__ ssrc, const float* __restrict__ sdst,
                      const float* __restrict__ b_gat, ushort_t* __restrict__ hb,
                      float* __restrict__ y, int N){
  int n = blockIdx.x*4 + (threadIdx.x >> 6);
  int l = threadIdx.x & 63;
  if (n >= N) return;
  int rs = rowp[n], re = rowp[n+1];
  float es = ssrc[n] + sdst[n];
  es = (es >= 0.f) ? es : NEG_SLOPE*es;
  float m = es;
  for (int j = rs + l; j < re; j += 64) m = fmaxf(m, col_e[j]);
  #pragma unroll
  for (int off = 32; off >= 1; off >>= 1) m = fmaxf(m, __shfl_xor(m, off, 64));
  float s = 0.f;
  for (int j = rs + l; j < re; j += 64) s += __expf(col_e[j] - m);
  #pragma unroll
  for (int off = 32; off >= 1; off >>= 1) s += __shfl_xor(s, off, 64);
  s += __expf(es - m);
  float inv = 1.f / s;
  float a0 = __expf(es - m) * inv;

  int sub = l >> 4, q = l & 15;
  const uint4* x16 = (const uint4*)xb;
  float acc[8] = {0.f,0.f,0.f,0.f,0.f,0.f,0.f,0.f};
  int deg = re - rs;
  int iters = (deg + 3) >> 2;
  for (int i = 0; i < iters; i++){
    int edge = rs + (i << 2) + sub;
    float a = 0.f; int sidx = n;
    if (edge < re){ sidx = col_src[edge]; a = __expf(col_e[edge] - m) * inv; }
    uint4 v = x16[(size_t)sidx*16 + q];
    fma8(acc, v, a);
  }
  #pragma unroll
  for (int j = 0; j < 8; j++){
    acc[j] += __shfl_xor(acc[j], 16, 64);
    acc[j] += __shfl_xor(acc[j], 32, 64);
  }
  if (sub == 0){
    uint4 v = x16[(size_t)n*16 + q];
    fma8(acc, v, a0);
    float4 b0 = ((const float4*)b_gat)[q*2];
    float4 b1 = ((const float4*)b_gat)[q*2 + 1];
    acc[0]+=b0.x; acc[1]+=b0.y; acc[2]+=b0.z; acc[3]+=b0.w;
    acc[4]+=b1.x; acc[5]+=b1.y; acc[6]+=b1.z; acc[7]+=b1.w;
    ((uint4*)hb)[(size_t)n*16 + q] = pack8(acc);
    float4* y4 = (float4*)y;
    y4[(size_t)n*32 + q*2]     = make_float4(acc[0], acc[1], acc[2], acc[3]);
    y4[(size_t)n*32 + q*2 + 1] = make_float4(acc[4], acc[5], acc[6], acc[7]);
  }
}

// ---------------- GCN aggregation + ReLU + JK max (verified round 2) ----------------
__global__ void k_gcn(const ushort_t* __restrict__ zb, const int* __restrict__ rowp,
                      const int* __restrict__ col_src, const float* __restrict__ col_norm,
                      const float* __restrict__ dinv, const float* __restrict__ bias,
                      ushort_t* __restrict__ hb, float* __restrict__ y, int N){
  int n = blockIdx.x*4 + (threadIdx.x >> 6);
  int l = threadIdx.x & 63;
  if (n >= N) return;
  int rs = rowp[n], re = rowp[n+1];
  float di = dinv[n];
  float sn = di * di;
  int sub = l >> 4, q = l & 15;
  const uint4* z16 = (const uint4*)zb;
  float acc[8] = {0.f,0.f,0.f,0.f,0.f,0.f,0.f,0.f};
  int deg = re - rs;
  int iters = (deg + 3) >> 2;
  for (int i = 0; i < iters; i++){
    int edge = rs + (i << 2) + sub;
    float a = 0.f; int sidx = n;
    if (edge < re){ sidx = col_src[edge]; a = col_norm[edge]; }
    uint4 v = z16[(size_t)sidx*16 + q];
    fma8(acc, v, a);
  }
  #pragma unroll
  for (int j = 0; j < 8; j++){
    acc[j] += __shfl_xor(acc[j], 16, 64);
    acc[j] += __shfl_xor(acc[j], 32, 64);
  }
  if (sub == 0){
    uint4 v = z16[(size_t)n*16 + q];
    fma8(acc, v, sn);
    float4 b0 = ((const float4*)bias)[q*2];
    float4 b1 = ((const float4*)bias)[q*2 + 1];
    acc[0]=fmaxf(acc[0]+b0.x,0.f); acc[1]=fmaxf(acc[1]+b0.y,0.f);
    acc[2]=fmaxf(acc[2]+b0.z,0.f); acc[3]=fmaxf(acc[3]+b0.w,0.f);
    acc[4]=fmaxf(acc[4]+b1.x,0.f); acc[5]=fmaxf(acc[5]+b1.y,0.f);
    acc[6]=fmaxf(acc[6]+b1.z,0.f); acc[7]=fmaxf(acc[7]+b1.w,0.f);
    ((uint4*)hb)[(size_t)n*16 + q] = pack8(acc);
    float4* y4 = (float4*)y;
    float4 y0 = y4[(size_t)n*32 + q*2];
    float4 y1 = y4[(size_t)n*32 + q*2 + 1];
    y0.x=fmaxf(y0.x,acc[0]); y0.y=fmaxf(y0.y,acc[1]); y0.z=fmaxf(y0.z,acc[2]); y0.w=fmaxf(y0.w,acc[3]);
    y1.x=fmaxf(y1.x,acc[4]); y1.y=fmaxf(y1.y,acc[5]); y1.z=fmaxf(y1.z,acc[6]); y1.w=fmaxf(y1.w,acc[7]);
    y4[(size_t)n*32 + q*2]     = y0;
    y4[(size_t)n*32 + q*2 + 1] = y1;
  }
}

extern "C" void kernel_launch(void* const* d_in, const int* in_sizes, int n_in,
                              void* d_out, int out_size, void* d_ws, size_t ws_size,
                              hipStream_t stream){
  const float* x      = (const float*)d_in[0];
  const int*   eidx   = (const int*)d_in[1];
  const float* emask  = (const float*)d_in[2];
  const float* W_gat  = (const float*)d_in[3];
  const float* a_src  = (const float*)d_in[4];
  const float* a_dst  = (const float*)d_in[5];
  const float* b_gat  = (const float*)d_in[6];
  const float* W_gcn  = (const float*)d_in[7];
  const float* b_gcn  = (const float*)d_in[8];
  int N = in_sizes[0] / HIDDEN;
  int E = in_sizes[1] / 2;
  const int* src = eidx;
  const int* dst = eidx + E;

  char* p = (char*)d_ws;
  auto carve = [&](size_t bytes)->char*{ char* q = p; p += align_up(bytes, 512); return q; };
  ushort_t* xb   = (ushort_t*)carve((size_t)N*HIDDEN*2);
  ushort_t* zb   = (ushort_t*)carve((size_t)N*HIDDEN*2);
  ushort_t* hb   = (ushort_t*)carve((size_t)N*HIDDEN*2);
  ushort_t* Wt   = (ushort_t*)carve((size_t)4*HIDDEN*HIDDEN*2);
  float* ssrc    = (float*)carve((size_t)N*4);
  float* sdst    = (float*)carve((size_t)N*4);
  float* dinv    = (float*)carve((size_t)N*4);
  int*   rowp    = (int*)  carve((size_t)(N+1)*4);
  int*   col_src = (int*)  carve((size_t)E*4);
  float* col_w   = (float*)carve((size_t)E*4);
  float* col_norm= (float*)carve((size_t)E*4);
  float* col_e   = (float*)carve((size_t)E*4);
  unsigned* tpk  = (unsigned*)carve((size_t)E*4);
  float* tw      = (float*)carve((size_t)E*4);
  int nbkt = (N + 255) >> 8;                       // 196
  int M    = nbkt * P_SORT;                        // 50176
  int*   bcnt  = (int*)carve((size_t)M*4);
  int*   ebase = (int*)carve((size_t)M*4);
  int nbs = (M + 255) / 256;
  int*   blockSums = (int*)carve((size_t)nbs*4);
  int*   blockOffs = (int*)carve((size_t)nbs*4);
  (void)ws_size; (void)n_in; (void)out_size;

  int epb = (E + P_SORT - 1) / P_SORT;
  int gb  = (N + 127) / 128;
  int nwb = (N + 3) / 4;
  int nqb = (N + 15) / 16;
  long n2 = (long)N*64;
  int cb  = (int)((n2 + 255) / 256);

  // CSR build (atomic-free, full-chip)
  k_b1cnt  <<<P_SORT, 256, 0, stream>>>(dst, bcnt, E, epb, nbkt);
  k_scan1  <<<nbs, 256, 0, stream>>>(bcnt, ebase, blockSums, M);
  k_scan2  <<<1,   256, 0, stream>>>(blockSums, blockOffs, nbs);
  k_scanex <<<nbs, 256, 0, stream>>>(ebase, bcnt, blockOffs, M);
  k_b1place<<<P_SORT, 256, 0, stream>>>(src, dst, emask, ebase, tpk, tw, E, epb);
  k_b2     <<<nbkt, 256, 0, stream>>>(tpk, tw, ebase, col_src, col_w, rowp, dinv, N, E, nbkt);

  // features
  k_cast_x<<<cb, 256, 0, stream>>>(x, (unsigned*)xb, n2);
  k_cast_w<<<(4*HIDDEN*HIDDEN)/256, 256, 0, stream>>>(W_gat, W_gcn, Wt);

  k_gemm <<<gb, 256, 0, stream>>>(xb, Wt, zb, N);                 // xp = x @ W_gat
  k_sdots<<<nwb,256, 0, stream>>>((const unsigned*)zb, a_src, a_dst, ssrc, sdst, N);
  k_edges<<<nqb,256, 0, stream>>>(rowp, col_src, col_w, dinv, ssrc, sdst, col_norm, col_e, N);

  k_gat  <<<nwb,256, 0, stream>>>(zb, rowp, col_src, col_e, ssrc, sdst,
                                  b_gat, hb, (float*)d_out, N);
  for (int l = 0; l < 3; l++){
    k_gemm<<<gb, 256, 0, stream>>>(hb, Wt + (size_t)(l+1)*HIDDEN*HIDDEN, zb, N);
    k_gcn <<<nwb,256, 0, stream>>>(zb, rowp, col_src, col_norm, dinv,
                                   b_gcn + (size_t)l*HIDDEN, hb, (float*)d_out, N);
  }
}